// Round 3
// baseline (3390.971 us; speedup 1.0000x reference)
//
#include <hip/hip_runtime.h>

typedef _Float16 half8 __attribute__((ext_vector_type(8)));
typedef float f32x4 __attribute__((ext_vector_type(4)));

#define B_SZ   2048
#define T_SZ   128
#define IN_SZ  64
#define H_SZ   256
#define G4     1024
#define NB     8        // col-blocks per batch group
#define NGRP   32       // batch groups (64 rows each)
#define NTHR   512

__device__ __forceinline__ float sigmoidf_(float x) { return 1.0f / (1.0f + __expf(-x)); }
__device__ __forceinline__ float tanhf_(float x) { return 1.0f - 2.0f / (__expf(2.0f * x) + 1.0f); }

// Repack W -> fp16, tile/fragment-ordered for the SWAPPED GEMM (A = W).
// Tile TI = nbk*8 + sub covers h-cols [nbk*32 + sub*4, +4) x 4 gates.
// Tile row m (0..15): gate q = m&3, col-sub cs = m>>2 -> orig gate row
// grow = q*256 + nbk*32 + sub*4 + cs.
// Frag storage: Wr[((TI*10+kt)*64 + lane)*8]; lane l: row m=l&15, k=kt*32+(l>>4)*8..+8.
__global__ void prep_kernel(const float* __restrict__ W_ih, const float* __restrict__ W_hh,
                            const float* __restrict__ b_ih, const float* __restrict__ b_hh,
                            _Float16* __restrict__ Wr, float* __restrict__ biasr) {
  const int tid = blockIdx.x * blockDim.x + threadIdx.x;   // 0..40959
  if (tid < G4) {
    const int TI = tid >> 4, m = tid & 15;
    const int q = m & 3, cs = m >> 2, nbk = TI >> 3, sub = TI & 7;
    const int grow = q * 256 + nbk * 32 + sub * 4 + cs;
    biasr[tid] = b_ih[grow] + b_hh[grow];
  }
  if (tid >= 64 * 10 * 64) return;
  const int l = tid & 63, kt = (tid >> 6) % 10, TI = tid / 640;
  const int lm = l & 15, lk = l >> 4;
  const int q = lm & 3, cs = lm >> 2, nbk = TI >> 3, sub = TI & 7;
  const int grow = q * 256 + nbk * 32 + sub * 4 + cs;
  const int k0 = kt * 32 + lk * 8;
  _Float16 v[8];
  #pragma unroll
  for (int kk = 0; kk < 8; ++kk) {
    const int k = k0 + kk;
    v[kk] = (_Float16)((k < IN_SZ) ? W_ih[grow * IN_SZ + k] : W_hh[grow * H_SZ + k - IN_SZ]);
  }
  *(half8*)&Wr[((size_t)(TI * 10 + kt) * 64 + l) * 8] = *(half8*)v;
}

// Persistent recurrence. Block b: group g = b>>3 (batch rows [g*64,+64)),
// nbk = b&7 (h-cols [nbk*32,+32)). Wave w: bt = w&3 (16 batch rows),
// gh = w>>2 (gate-tiles gh*4..+4). W resident: kt2..9 in VGPR, kt0..1 in LDS.
// h exchange: hbuf[t&1], flags[g*128+t] counts writer blocks (release/acquire).
__global__ __launch_bounds__(NTHR, 2)
void lstm_kernel(const float* __restrict__ x,
                 const _Float16* __restrict__ Wr,
                 const float* __restrict__ biasr,
                 _Float16* __restrict__ hbuf,
                 int* __restrict__ flags) {
  __shared__ __align__(16) _Float16 Wlds[8 * 2 * 512];   // [sub][kt0/1][lane*8] = 16 KB

  const int tid = threadIdx.x;
  const int l = tid & 63;
  const int w = tid >> 6;
  const int lm = l & 15, lk = l >> 4;
  const int bt = w & 3, gh = w >> 2;
  const int g = blockIdx.x >> 3, nbk = blockIdx.x & 7;
  const int brow = g * 64 + bt * 16 + lm;     // batch row this lane covers (B-frag col)

  // stage Wlds (kt 0,1 for all 8 subs of this nbk)
  {
    const int sub = tid >> 6;
    #pragma unroll
    for (int kt = 0; kt < 2; ++kt)
      *(half8*)&Wlds[((sub * 2 + kt) * 64 + l) * 8] =
          *(const half8*)&Wr[(((size_t)(nbk * 8 + sub) * 10 + kt) * 64 + l) * 8];
  }

  // register-resident W: kt 2..9 for this wave's 4 gate-tiles
  half8 Wf[4][8];
  #pragma unroll
  for (int ti = 0; ti < 4; ++ti) {
    const size_t tb = ((size_t)((nbk * 8 + gh * 4 + ti) * 10)) * 512 + (size_t)l * 8;
    #pragma unroll
    for (int j = 0; j < 8; ++j)
      Wf[ti][j] = *(const half8*)&Wr[tb + (size_t)(j + 2) * 512];
  }

  f32x4 bias[4];
  #pragma unroll
  for (int ti = 0; ti < 4; ++ti)
    bias[ti] = *(const f32x4*)&biasr[(nbk * 8 + gh * 4 + ti) * 16 + lk * 4];

  const float* xlane = x + (size_t)brow * T_SZ * IN_SZ + lk * 8;
  const int hcol0 = nbk * 32 + gh * 16 + lk;   // + ti*4
  int* flagg = flags + g * 128;

  __syncthreads();   // Wlds ready

  float cst[4] = {0.f, 0.f, 0.f, 0.f};

  for (int t = 0; t < T_SZ; ++t) {
    const int par = t & 1;
    const _Float16* hprev = hbuf + (size_t)(par ^ 1) * (B_SZ * H_SZ) + (size_t)brow * H_SZ + lk * 8;

    // x-part B-frags (kt0,1) — independent of h; issued before the spin
    half8 bx0, bx1;
    {
      const float* xp = xlane + t * IN_SZ;
      const f32x4 a0 = *(const f32x4*)(xp);
      const f32x4 a1 = *(const f32x4*)(xp + 4);
      const f32x4 b0 = *(const f32x4*)(xp + 32);
      const f32x4 b1 = *(const f32x4*)(xp + 36);
      #pragma unroll
      for (int i = 0; i < 4; ++i) {
        bx0[i] = (_Float16)a0[i]; bx0[4 + i] = (_Float16)a1[i];
        bx1[i] = (_Float16)b0[i]; bx1[4 + i] = (_Float16)b1[i];
      }
    }

    f32x4 acc[4];
    #pragma unroll
    for (int ti = 0; ti < 4; ++ti) acc[ti] = (f32x4){0.f, 0.f, 0.f, 0.f};

    // kt0,1 MFMAs (W from LDS) — overlap with waiting
    #pragma unroll
    for (int ti = 0; ti < 4; ++ti) {
      const half8 w0 = *(const half8*)&Wlds[(((gh * 4 + ti) * 2 + 0) * 64 + l) * 8];
      acc[ti] = __builtin_amdgcn_mfma_f32_16x16x32_f16(w0, bx0, acc[ti], 0, 0, 0);
    }
    #pragma unroll
    for (int ti = 0; ti < 4; ++ti) {
      const half8 w1 = *(const half8*)&Wlds[(((gh * 4 + ti) * 2 + 1) * 64 + l) * 8];
      acc[ti] = __builtin_amdgcn_mfma_f32_16x16x32_f16(w1, bx1, acc[ti], 0, 0, 0);
    }

    if (t > 0) {
      if (tid == 0) {
        while (__hip_atomic_load(flagg + (t - 1), __ATOMIC_RELAXED, __HIP_MEMORY_SCOPE_AGENT) < NB)
          __builtin_amdgcn_s_sleep(1);
      }
      __syncthreads();
      __builtin_amdgcn_fence(__ATOMIC_ACQUIRE, "agent");   // invalidate L1/L2 -> read fresh h
    }

    // h-part: kt2..9, rolling global loads from hprev
    #define MF(j, hb) { _Pragma("unroll") \
      for (int ti = 0; ti < 4; ++ti) \
        acc[ti] = __builtin_amdgcn_mfma_f32_16x16x32_f16(Wf[ti][j], hb, acc[ti], 0, 0, 0); }
    half8 h0 = *(const half8*)(hprev);
    half8 h1 = *(const half8*)(hprev + 32);
    half8 h2 = *(const half8*)(hprev + 64);
    half8 h3 = *(const half8*)(hprev + 96);
    MF(0, h0); h0 = *(const half8*)(hprev + 128);
    MF(1, h1); h1 = *(const half8*)(hprev + 160);
    MF(2, h2); h2 = *(const half8*)(hprev + 192);
    MF(3, h3); h3 = *(const half8*)(hprev + 224);
    MF(4, h0);
    MF(5, h1);
    MF(6, h2);
    MF(7, h3);
    #undef MF

    // cell update: acc[ti][q] = gate q for (batch brow, h-col hcol0 + ti*4)
    _Float16* hcur = hbuf + (size_t)par * (B_SZ * H_SZ) + (size_t)brow * H_SZ;
    #pragma unroll
    for (int ti = 0; ti < 4; ++ti) {
      const float iv = sigmoidf_(acc[ti][0] + bias[ti][0]);
      const float fv = sigmoidf_(acc[ti][1] + bias[ti][1]);
      const float gv = tanhf_   (acc[ti][2] + bias[ti][2]);
      const float ov = sigmoidf_(acc[ti][3] + bias[ti][3]);
      const float cn = fv * cst[ti] + iv * gv;
      cst[ti] = cn;
      hcur[hcol0 + ti * 4] = (_Float16)(ov * tanhf_(cn));
    }

    __syncthreads();   // drains each wave's vmcnt -> all h stores in L2
    if (tid == 0) {
      __builtin_amdgcn_fence(__ATOMIC_RELEASE, "agent");   // wbl2: flush to IC
      __hip_atomic_fetch_add(flagg + t, 1, __ATOMIC_RELAXED, __HIP_MEMORY_SCOPE_AGENT);
    }
  }
}

__global__ void fc_kernel(const _Float16* __restrict__ hbuf, const float* __restrict__ fcW,
                          const float* __restrict__ fcb, float* __restrict__ out) {
  const int b = blockIdx.x * 256 + threadIdx.x;
  if (b >= B_SZ) return;
  const _Float16* hr = hbuf + (size_t)(B_SZ * H_SZ) + (size_t)b * H_SZ;   // h_127 parity 1
  float s = 0.f;
  #pragma unroll
  for (int k = 0; k < H_SZ; k += 8) {
    const half8 v = *(const half8*)&hr[k];
    #pragma unroll
    for (int j = 0; j < 8; ++j) s += (float)v[j] * fcW[k + j];
  }
  out[b] = s + fcb[0];
}

extern "C" void kernel_launch(void* const* d_in, const int* in_sizes, int n_in,
                              void* d_out, int out_size, void* d_ws, size_t ws_size,
                              hipStream_t stream) {
  const float* x    = (const float*)d_in[0];
  const float* W_ih = (const float*)d_in[1];
  const float* W_hh = (const float*)d_in[2];
  const float* b_ih = (const float*)d_in[3];
  const float* b_hh = (const float*)d_in[4];
  const float* fcW  = (const float*)d_in[5];
  const float* fcb  = (const float*)d_in[6];
  float* out = (float*)d_out;

  // ws: Wr 655360 B | biasr 4096 B | hbuf 2 MB | flags 16 KB  (~2.8 MB)
  char* ws = (char*)d_ws;
  _Float16* Wr   = (_Float16*)ws;
  float* biasr   = (float*)(ws + 655360);
  _Float16* hbuf = (_Float16*)(ws + 659456);
  int* flags     = (int*)(ws + 659456 + 2097152);

  hipMemsetAsync(hbuf, 0, (size_t)2 * B_SZ * H_SZ * sizeof(_Float16), stream);
  hipMemsetAsync(flags, 0, NGRP * T_SZ * sizeof(int), stream);
  hipLaunchKernelGGL(prep_kernel, dim3(160), dim3(256), 0, stream,
                     W_ih, W_hh, b_ih, b_hh, Wr, biasr);
  hipLaunchKernelGGL(lstm_kernel, dim3(256), dim3(NTHR), 0, stream,
                     x, Wr, biasr, hbuf, flags);
  hipLaunchKernelGGL(fc_kernel, dim3(8), dim3(256), 0, stream,
                     hbuf, fcW, fcb, out);
}

// Round 4
// 1195.591 us; speedup vs baseline: 2.8362x; 2.8362x over previous
//
#include <hip/hip_runtime.h>

typedef _Float16 half8 __attribute__((ext_vector_type(8)));
typedef float f32x4 __attribute__((ext_vector_type(4)));

#define B_SZ   2048
#define T_SZ   128
#define IN_SZ  64
#define H_SZ   256
#define G4     1024          // 4*H
#define KTOT   320           // IN + H
#define KT_N   10            // K tiles of 32
#define M_BLK  8
#define NBLK   (B_SZ / M_BLK)   // 256 blocks -> 1 per CU
#define NTHR   512              // 8 waves
#define A_PAD  328              // LDS A row stride in halves
#define KT_REG 3                // kt 0..2 in VGPRs (96 VGPR/wave)
#define KT_LDS 2                // kt 3..4 in LDS (128 KB/block)

__device__ __forceinline__ float sigmoidf_(float x) { return 1.0f / (1.0f + __expf(-x)); }
__device__ __forceinline__ float tanhf_(float x) { return 1.0f - 2.0f / (__expf(2.0f * x) + 1.0f); }

// Repack [W_ih | W_hh] -> fp16, gate-reordered, MFMA-fragment-ordered.
// rp = w*128 + q*32 + j  ->  original gate row g = q*256 + w*32 + j.
// Frag (nb,kt): flat [(nb*10+kt)*64 + lane]*8 halves; lane l holds row
// nb*16+(l&15), k = kt*32 + (l>>4)*8 .. +8.
__global__ void prep_kernel(const float* __restrict__ W_ih,
                            const float* __restrict__ W_hh,
                            const float* __restrict__ b_ih,
                            const float* __restrict__ b_hh,
                            _Float16* __restrict__ Wpp,
                            float* __restrict__ biasp) {
  const int tid = blockIdx.x * blockDim.x + threadIdx.x;
  if (tid < G4) {
    const int rp = tid;
    const int w = rp >> 7, q = (rp >> 5) & 3, j = rp & 31;
    const int g = q * 256 + w * 32 + j;
    biasp[rp] = b_ih[g] + b_hh[g];
  }
  const int l  = tid & 63;
  const int kt = (tid >> 6) % KT_N;
  const int nb = tid / (64 * KT_N);
  if (nb >= G4 / 16) return;
  const int rp = nb * 16 + (l & 15);
  const int w = rp >> 7, q = (rp >> 5) & 3, j = rp & 31;
  const int g = q * 256 + w * 32 + j;
  const int k0 = kt * 32 + (l >> 4) * 8;
  _Float16 v[8];
  #pragma unroll
  for (int kk = 0; kk < 8; ++kk) {
    const int k = k0 + kk;
    const float f = (k < IN_SZ) ? W_ih[g * IN_SZ + k]
                                : W_hh[g * H_SZ + (k - IN_SZ)];
    v[kk] = (_Float16)f;
  }
  *(half8*)(Wpp + ((size_t)(nb * KT_N + kt) * 64 + l) * 8) = *(half8*)v;
}

__global__ __launch_bounds__(NTHR, 2)
void lstm_kernel(const float* __restrict__ x,
                 const _Float16* __restrict__ Wpp,
                 const float* __restrict__ biasp,
                 const float* __restrict__ fcW,
                 const float* __restrict__ fcb,
                 float* __restrict__ out) {
  // Abuf only 8 rows: acc rows 8..15 are dead (M_BLK=8), lanes lm>=8 read lm&7
  __shared__ __align__(16) _Float16 Abuf[2][8][A_PAD];    // 10496 B
  __shared__ __align__(16) _Float16 Blds[128 * 512];      // 131072 B
  __shared__ float red[M_BLK][16];                        // 512 B

  const int tid = threadIdx.x;
  const int l   = tid & 63;
  const int w   = tid >> 6;     // wave 0..7 -> owns h-cols [w*32, w*32+32)
  const int lm  = l & 15;
  const int lk  = l >> 4;
  const int r0  = blockIdx.x * M_BLK;

  {
    _Float16* ab = &Abuf[0][0][0];
    for (int i = tid; i < 2 * 8 * A_PAD; i += NTHR) ab[i] = (_Float16)0.0f;
  }

  float bias[8];
  #pragma unroll
  for (int nt = 0; nt < 8; ++nt) bias[nt] = biasp[w * 128 + nt * 16 + lm];

  const _Float16* wbase = Wpp + (size_t)w * 8 * KT_N * 512 + (size_t)l * 8;

  // register-resident B: kt 0..2
  half8 bres[8][KT_REG];
  #pragma unroll
  for (int nt = 0; nt < 8; ++nt)
    #pragma unroll
    for (int kt = 0; kt < KT_REG; ++kt)
      bres[nt][kt] = *(const half8*)(wbase + (size_t)(nt * KT_N + kt) * 512);

  __syncthreads();  // zeroing visible

  // stage x_0 into buf 0
  {
    const int r = tid >> 6, cc = tid & 63;
    Abuf[0][r][cc] = (_Float16)x[((size_t)(r0 + r) * T_SZ) * IN_SZ + cc];
  }
  // LDS-resident B: kt 3..4
  #pragma unroll
  for (int nt = 0; nt < 8; ++nt)
    #pragma unroll
    for (int j = 0; j < KT_LDS; ++j)
      *(half8*)&Blds[((w * 16 + nt * 2 + j) * 512) + l * 8] =
          *(const half8*)(wbase + (size_t)(nt * KT_N + KT_REG + j) * 512);

  __syncthreads();

  float cst[2][4] = {};

  for (int t = 0; t < T_SZ; ++t) {
    const _Float16 (*Ain)[A_PAD] = Abuf[t & 1];
    _Float16 (*Aout)[A_PAD] = Abuf[(t + 1) & 1];

    // deep prefetch: issue ALL kt5,6,7 streamed loads up front (24 in flight)
    half8 st0[8], st1[8], st2[8];
    #pragma unroll
    for (int nt = 0; nt < 8; ++nt)
      st0[nt] = *(const half8*)(wbase + (size_t)(nt * KT_N + 5) * 512);
    #pragma unroll
    for (int nt = 0; nt < 8; ++nt)
      st1[nt] = *(const half8*)(wbase + (size_t)(nt * KT_N + 6) * 512);
    #pragma unroll
    for (int nt = 0; nt < 8; ++nt)
      st2[nt] = *(const half8*)(wbase + (size_t)(nt * KT_N + 7) * 512);

    // stage x_{t+1} (overlaps GEMM)
    if (t + 1 < T_SZ) {
      const int r = tid >> 6, cc = tid & 63;
      Aout[r][cc] = (_Float16)x[((size_t)(r0 + r) * T_SZ + (t + 1)) * IN_SZ + cc];
    }

    #define LA(kt) (*(const half8*)&Ain[lm & 7][(kt) * 32 + lk * 8])
    half8 a_cur = LA(0), a_n1 = LA(1), a_n2 = LA(2);

    f32x4 acc[8];
    #pragma unroll
    for (int nt = 0; nt < 8; ++nt) acc[nt] = (f32x4){0.f, 0.f, 0.f, 0.f};

    // kt 0..2: register-resident W
    #pragma unroll
    for (int nt = 0; nt < 8; ++nt)
      acc[nt] = __builtin_amdgcn_mfma_f32_16x16x32_f16(a_cur, bres[nt][0], acc[nt], 0, 0, 0);
    a_cur = a_n1; a_n1 = a_n2; a_n2 = LA(3);
    #pragma unroll
    for (int nt = 0; nt < 8; ++nt)
      acc[nt] = __builtin_amdgcn_mfma_f32_16x16x32_f16(a_cur, bres[nt][1], acc[nt], 0, 0, 0);
    a_cur = a_n1; a_n1 = a_n2; a_n2 = LA(4);
    #pragma unroll
    for (int nt = 0; nt < 8; ++nt)
      acc[nt] = __builtin_amdgcn_mfma_f32_16x16x32_f16(a_cur, bres[nt][2], acc[nt], 0, 0, 0);
    a_cur = a_n1; a_n1 = a_n2; a_n2 = LA(5);

    // kt 3..4: LDS-resident W
    #pragma unroll
    for (int nt = 0; nt < 8; ++nt) {
      const half8 bl = *(const half8*)&Blds[((w * 16 + nt * 2 + 0) * 64 + l) * 8];
      acc[nt] = __builtin_amdgcn_mfma_f32_16x16x32_f16(a_cur, bl, acc[nt], 0, 0, 0);
    }
    a_cur = a_n1; a_n1 = a_n2; a_n2 = LA(6);
    #pragma unroll
    for (int nt = 0; nt < 8; ++nt) {
      const half8 bl = *(const half8*)&Blds[((w * 16 + nt * 2 + 1) * 64 + l) * 8];
      acc[nt] = __builtin_amdgcn_mfma_f32_16x16x32_f16(a_cur, bl, acc[nt], 0, 0, 0);
    }
    a_cur = a_n1; a_n1 = a_n2; a_n2 = LA(7);

    // kt 5: consume st0, refill with kt8
    #pragma unroll
    for (int nt = 0; nt < 8; ++nt)
      acc[nt] = __builtin_amdgcn_mfma_f32_16x16x32_f16(a_cur, st0[nt], acc[nt], 0, 0, 0);
    #pragma unroll
    for (int nt = 0; nt < 8; ++nt)
      st0[nt] = *(const half8*)(wbase + (size_t)(nt * KT_N + 8) * 512);
    a_cur = a_n1; a_n1 = a_n2; a_n2 = LA(8);

    // kt 6: consume st1, refill with kt9
    #pragma unroll
    for (int nt = 0; nt < 8; ++nt)
      acc[nt] = __builtin_amdgcn_mfma_f32_16x16x32_f16(a_cur, st1[nt], acc[nt], 0, 0, 0);
    #pragma unroll
    for (int nt = 0; nt < 8; ++nt)
      st1[nt] = *(const half8*)(wbase + (size_t)(nt * KT_N + 9) * 512);
    a_cur = a_n1; a_n1 = a_n2; a_n2 = LA(9);

    // kt 7, 8, 9
    #pragma unroll
    for (int nt = 0; nt < 8; ++nt)
      acc[nt] = __builtin_amdgcn_mfma_f32_16x16x32_f16(a_cur, st2[nt], acc[nt], 0, 0, 0);
    a_cur = a_n1; a_n1 = a_n2;
    #pragma unroll
    for (int nt = 0; nt < 8; ++nt)
      acc[nt] = __builtin_amdgcn_mfma_f32_16x16x32_f16(a_cur, st0[nt], acc[nt], 0, 0, 0);
    a_cur = a_n1;
    #pragma unroll
    for (int nt = 0; nt < 8; ++nt)
      acc[nt] = __builtin_amdgcn_mfma_f32_16x16x32_f16(a_cur, st1[nt], acc[nt], 0, 0, 0);
    #undef LA

    // cell update: acc tile nt = q*2 + jh; h-col = w*32 + jh*16 + lm; rows lk*4+r (lk<2)
    #pragma unroll
    for (int jh = 0; jh < 2; ++jh) {
      #pragma unroll
      for (int r = 0; r < 4; ++r) {
        const float iv = sigmoidf_(acc[0 + jh][r] + bias[0 + jh]);
        const float fv = sigmoidf_(acc[2 + jh][r] + bias[2 + jh]);
        const float gv = tanhf_   (acc[4 + jh][r] + bias[4 + jh]);
        const float ov = sigmoidf_(acc[6 + jh][r] + bias[6 + jh]);
        const float cn = fv * cst[jh][r] + iv * gv;
        cst[jh][r] = cn;
        const float hv = ov * tanhf_(cn);
        if (lk < 2) {
          const int m   = lk * 4 + r;
          const int col = w * 32 + jh * 16 + lm;
          Aout[m][IN_SZ + col] = (_Float16)hv;
        }
      }
    }
    __syncthreads();
  }

  // out[r] = h_last[r,:] . fcW + fcb  (h_last lives in Abuf[0] h-region)
  if (tid < 128) {
    const int r = tid >> 4, c0 = tid & 15;
    float p = 0.f;
    #pragma unroll
    for (int cc = 0; cc < 16; ++cc) {
      const int col = c0 + cc * 16;
      p += (float)Abuf[0][r][IN_SZ + col] * fcW[col];
    }
    red[r][c0] = p;
  }
  __syncthreads();
  if (tid < M_BLK) {
    float s = 0.f;
    #pragma unroll
    for (int k = 0; k < 16; ++k) s += red[tid][k];
    out[r0 + tid] = s + fcb[0];
  }
}

extern "C" void kernel_launch(void* const* d_in, const int* in_sizes, int n_in,
                              void* d_out, int out_size, void* d_ws, size_t ws_size,
                              hipStream_t stream) {
  const float* x    = (const float*)d_in[0];
  const float* W_ih = (const float*)d_in[1];
  const float* W_hh = (const float*)d_in[2];
  const float* b_ih = (const float*)d_in[3];
  const float* b_hh = (const float*)d_in[4];
  const float* fcW  = (const float*)d_in[5];
  const float* fcb  = (const float*)d_in[6];
  float* out = (float*)d_out;

  _Float16* Wpp = (_Float16*)d_ws;
  float* biasp  = (float*)((char*)d_ws + (size_t)G4 * KTOT * sizeof(_Float16));

  hipLaunchKernelGGL(prep_kernel, dim3(160), dim3(256), 0, stream,
                     W_ih, W_hh, b_ih, b_hh, Wpp, biasp);
  hipLaunchKernelGGL(lstm_kernel, dim3(NBLK), dim3(NTHR), 0, stream,
                     x, Wpp, biasp, fcW, fcb, out);
}